// Round 10
// baseline (454.822 us; speedup 1.0000x reference)
//
#include <hip/hip_runtime.h>
#include <hip/hip_bf16.h>

// ---------------------------------------------------------------------------
// ROLAND-style GNN forward. Round 9: register-only streaming GEMM -- no LDS,
// no barriers. Block = 4 waves = 4 column panels of one 32-row tile (A read
// once per block, shared via L1/L2). A-frags loaded directly from global in
// MFMA fragment layout; B-frags from L2-hot transposed hi/lo weights; K fully
// unrolled. Bucketed CSR build; bf16 CSR gather with 8-deep ILP.
// ---------------------------------------------------------------------------

typedef unsigned short ushort_t;
typedef __attribute__((ext_vector_type(8))) short s8v;   // 8 bf16 (4 VGPRs)
typedef __attribute__((ext_vector_type(4))) float f4;    // MFMA accumulator

#define BSHIFT 8                       // nodes per bucket = 256 (N<=65536)

__device__ __forceinline__ void bsplit(float v, ushort_t& hi, ushort_t& lo) {
    unsigned u = __float_as_uint(v);
    unsigned rh = u + 0x7FFFu + ((u >> 16) & 1u);
    hi = (ushort_t)(rh >> 16);
    float fh = __uint_as_float((unsigned)hi << 16);
    float d = v - fh;
    unsigned u2 = __float_as_uint(d);
    unsigned rl = u2 + 0x7FFFu + ((u2 >> 16) & 1u);
    lo = (ushort_t)(rl >> 16);
}

__device__ __forceinline__ ushort_t f2bf(float v) {
    unsigned u = __float_as_uint(v);
    return (ushort_t)((u + 0x7FFFu + ((u >> 16) & 1u)) >> 16);
}

__device__ __forceinline__ s8v cvt8(f4 v0, f4 v1) {
    ushort_t hb[8];
    hb[0] = f2bf(v0.x); hb[1] = f2bf(v0.y); hb[2] = f2bf(v0.z); hb[3] = f2bf(v0.w);
    hb[4] = f2bf(v1.x); hb[5] = f2bf(v1.y); hb[6] = f2bf(v1.z); hb[7] = f2bf(v1.w);
    return *(s8v*)hb;
}

// ---------------- register-only streaming MFMA GEMM -------------------------
// C[M,Nout] = epilogue( A[M,K1] (++ A2[M,KW-K1]) @ W[KW,Nout] )
// grid.x = ceil(M/32); block = 4 waves, wave w = column panel w (NT*16 cols).
// Requires Nout == 64*NT. Wth/Wtl: [Nout][KW] bf16 transposed+split.
// A1BF: A1 is bf16. OUTMODE: 0 = fp32, 2 = bf16, 3 = fp32 + bf16 copy.
template <int NT, int KW, int K1, bool RELU, bool SCALE, bool DUAL, bool A1BF, int OUTMODE>
__global__ __launch_bounds__(256, 3) void gemm_reg(
    const float* __restrict__ A1f, const ushort_t* __restrict__ A1h,
    const float* __restrict__ A2f,
    const ushort_t* __restrict__ Wth, const ushort_t* __restrict__ Wtl,
    const float* __restrict__ bias, const float* __restrict__ rowscale,
    float* __restrict__ Cf, ushort_t* __restrict__ Ch,
    int M, int Nout)
{
    constexpr int K2 = KW - K1;
    const int lane  = threadIdx.x & 63;
    const int w     = threadIdx.x >> 6;
    const int rbase = blockIdx.x * 32;
    const int bn    = w * (NT * 16);
    if (rbase >= M) return;

    f4 acc[2][NT];
    const f4 zero = {0.f, 0.f, 0.f, 0.f};
#pragma unroll
    for (int mi = 0; mi < 2; ++mi)
#pragma unroll
        for (int ni = 0; ni < NT; ++ni) acc[mi][ni] = zero;

    const int r0 = min(rbase + (lane & 15), M - 1);
    const int r1 = min(rbase + 16 + (lane & 15), M - 1);
    const int kq = (lane >> 4) * 8;        // k-offset of this lane's 8 elems

#pragma unroll
    for (int ks = 0; ks < KW / 32; ++ks) {
        const int kb = ks * 32 + kq;
        s8v a0, a1;
        if (DUAL && ks * 32 >= K1) {
            const float* p0 = &A2f[(size_t)r0 * K2 + (kb - K1)];
            const float* p1 = &A2f[(size_t)r1 * K2 + (kb - K1)];
            a0 = cvt8(*(const f4*)p0, *(const f4*)(p0 + 4));
            a1 = cvt8(*(const f4*)p1, *(const f4*)(p1 + 4));
        } else if (A1BF) {
            a0 = *(const s8v*)&A1h[(size_t)r0 * K1 + kb];
            a1 = *(const s8v*)&A1h[(size_t)r1 * K1 + kb];
        } else {
            const float* p0 = &A1f[(size_t)r0 * K1 + kb];
            const float* p1 = &A1f[(size_t)r1 * K1 + kb];
            a0 = cvt8(*(const f4*)p0, *(const f4*)(p0 + 4));
            a1 = cvt8(*(const f4*)p1, *(const f4*)(p1 + 4));
        }
#pragma unroll
        for (int ni = 0; ni < NT; ++ni) {
            const int col = bn + ni * 16 + (lane & 15);
            const s8v bh = *(const s8v*)&Wth[(size_t)col * KW + kb];
            const s8v bl = *(const s8v*)&Wtl[(size_t)col * KW + kb];
            acc[0][ni] = __builtin_amdgcn_mfma_f32_16x16x32_bf16(a0, bh, acc[0][ni], 0, 0, 0);
            acc[0][ni] = __builtin_amdgcn_mfma_f32_16x16x32_bf16(a0, bl, acc[0][ni], 0, 0, 0);
            acc[1][ni] = __builtin_amdgcn_mfma_f32_16x16x32_bf16(a1, bh, acc[1][ni], 0, 0, 0);
            acc[1][ni] = __builtin_amdgcn_mfma_f32_16x16x32_bf16(a1, bl, acc[1][ni], 0, 0, 0);
        }
    }

    // ---- epilogue: C/D layout col=lane&15, row=(lane>>4)*4+reg ----
#pragma unroll
    for (int mi = 0; mi < 2; ++mi) {
#pragma unroll
        for (int reg = 0; reg < 4; ++reg) {
            const int row = rbase + mi * 16 + (lane >> 4) * 4 + reg;
            if (row >= M) continue;
            const float rs = SCALE ? rowscale[row] : 1.f;
#pragma unroll
            for (int ni = 0; ni < NT; ++ni) {
                const int col = bn + ni * 16 + (lane & 15);
                float v = acc[mi][ni][reg];
                if (SCALE) v *= rs;
                if (bias) v += bias[col];
                if (RELU) v = fmaxf(v, 0.f);
                if constexpr (OUTMODE == 2) {
                    Ch[(size_t)row * Nout + col] = f2bf(v);
                } else if constexpr (OUTMODE == 3) {
                    Cf[(size_t)row * Nout + col] = v;
                    Ch[(size_t)row * Nout + col] = f2bf(v);
                } else {
                    Cf[(size_t)row * Nout + col] = v;
                }
            }
        }
    }
}

// ---------------- weight transpose + split ---------------------------------
struct WDesc { const float* W; ushort_t* h; ushort_t* l; int K; int No; };
struct WAll { WDesc d[6]; };

__global__ void wtcvt_kernel(WAll wa) {
    WDesc d = wa.d[blockIdx.y];
    int e = blockIdx.x * blockDim.x + threadIdx.x;
    if (e >= d.K * d.No) return;
    int k = e / d.No, n = e - k * d.No;
    ushort_t h, l;
    bsplit(d.W[e], h, l);
    d.h[(size_t)n * d.K + k] = h;
    d.l[(size_t)n * d.K + k] = l;
}

// ---------------- bucketed CSR build ----------------------------------------
__global__ __launch_bounds__(256) void bcount_kernel(const int* __restrict__ dst,
                                                     int* __restrict__ bcount, int E, int NB) {
    __shared__ int cnt[256];
    const int t = threadIdx.x;
    if (t < NB) cnt[t] = 0;
    __syncthreads();
    for (int e = blockIdx.x * 256 + t; e < E; e += gridDim.x * 256)
        atomicAdd(&cnt[dst[e] >> BSHIFT], 1);
    __syncthreads();
    if (t < NB && cnt[t]) atomicAdd(&bcount[t], cnt[t]);
}

__global__ __launch_bounds__(256) void bscan_kernel(const int* __restrict__ bcount,
                                                    int* __restrict__ bbase,
                                                    int* __restrict__ bcursor, int NB, int E) {
    __shared__ int s[256];
    const int t = threadIdx.x;
    s[t] = (t < NB) ? bcount[t] : 0;
    __syncthreads();
    for (int off = 1; off < 256; off <<= 1) {
        int v = (t >= off) ? s[t - off] : 0;
        __syncthreads();
        s[t] += v;
        __syncthreads();
    }
    int excl = t ? s[t - 1] : 0;
    if (t < NB) { bbase[t] = excl; bcursor[t] = excl; }
    if (t == 0) bbase[NB] = E;
}

__global__ __launch_bounds__(256) void bpart_kernel(const int* __restrict__ src,
                                                    const int* __restrict__ dst,
                                                    int* __restrict__ bcursor,
                                                    unsigned* __restrict__ packed, int E, int NB) {
    __shared__ int cnt[256];
    __shared__ int cur[256];
    const int t = threadIdx.x;
    const int beg = blockIdx.x * 8192;
    const int end = min(beg + 8192, E);
    if (t < NB) cnt[t] = 0;
    __syncthreads();
    for (int e = beg + t; e < end; e += 256) atomicAdd(&cnt[dst[e] >> BSHIFT], 1);
    __syncthreads();
    if (t < NB && cnt[t]) cur[t] = atomicAdd(&bcursor[t], cnt[t]);
    __syncthreads();
    for (int e = beg + t; e < end; e += 256) {
        int d = dst[e];
        int b = d >> BSHIFT;
        int pos = atomicAdd(&cur[b], 1);
        packed[pos] = (unsigned)src[e] | ((unsigned)(d & ((1 << BSHIFT) - 1)) << 16);
    }
}

__global__ __launch_bounds__(256) void bbuild_kernel(const int* __restrict__ bbase,
                                                     const unsigned* __restrict__ packed,
                                                     int* __restrict__ col,
                                                     int* __restrict__ rowstart,
                                                     float* __restrict__ dinv, int N, int E) {
    __shared__ int ncnt[256];
    __shared__ int s[256];
    __shared__ int ncur[256];
    const int b = blockIdx.x;
    const int t = threadIdx.x;
    const int beg = bbase[b], end = bbase[b + 1];
    const int node0 = b << BSHIFT;
    const int nInB = min(256, N - node0);
    ncnt[t] = 0;
    __syncthreads();
    for (int e = beg + t; e < end; e += 256) atomicAdd(&ncnt[packed[e] >> 16], 1);
    __syncthreads();
    s[t] = ncnt[t];
    __syncthreads();
    for (int off = 1; off < 256; off <<= 1) {
        int v = (t >= off) ? s[t - off] : 0;
        __syncthreads();
        s[t] += v;
        __syncthreads();
    }
    int excl = t ? s[t - 1] : 0;
    if (t < nInB) {
        rowstart[node0 + t] = beg + excl;
        dinv[node0 + t] = rsqrtf((float)ncnt[t] + 1.0f);
    }
    ncur[t] = beg + excl;
    __syncthreads();
    for (int e = beg + t; e < end; e += 256) {
        unsigned p = packed[e];
        int pos = atomicAdd(&ncur[p >> 16], 1);
        col[pos] = (int)(p & 0xFFFFu);
    }
    if (b == 0 && t == 0) rowstart[N] = E;
}

// ---------------- CSR gather (bf16 in, bf16 out, 8-deep ILP) ----------------
template <int F>
__global__ __launch_bounds__(256) void gather_bf_kernel(const int* __restrict__ rowstart,
                                                        const int* __restrict__ col,
                                                        const float* __restrict__ dinv,
                                                        const ushort_t* __restrict__ hws,
                                                        const float* __restrict__ bias,
                                                        ushort_t* __restrict__ aggb, int N) {
    const int wave = threadIdx.x >> 6;
    const int lane = threadIdx.x & 63;
    const int d = blockIdx.x * 4 + wave;
    if (d >= N) return;
    const int beg = rowstart[d], end = rowstart[d + 1];
    const float dd = dinv[d];
    if (F == 128) {
        const unsigned* base = (const unsigned*)hws;   // 2 bf16 per uint
        unsigned sv = base[(size_t)d * 64 + lane];
        float ax = __uint_as_float(sv << 16);
        float ay = __uint_as_float(sv & 0xFFFF0000u);
        for (int e0 = beg; e0 < end; e0 += 64) {
            int nid = (e0 + lane < end) ? col[e0 + lane] : 0;
            int cnt = min(64, end - e0);
            int j = 0;
            for (; j + 8 <= cnt; j += 8) {
                unsigned u[8];
#pragma unroll
                for (int q = 0; q < 8; ++q) {
                    int s = __shfl(nid, j + q);
                    u[q] = base[(size_t)s * 64 + lane];
                }
#pragma unroll
                for (int q = 0; q < 8; ++q) {
                    ax += __uint_as_float(u[q] << 16);
                    ay += __uint_as_float(u[q] & 0xFFFF0000u);
                }
            }
            for (; j < cnt; ++j) {
                int s = __shfl(nid, j);
                unsigned uu = base[(size_t)s * 64 + lane];
                ax += __uint_as_float(uu << 16);
                ay += __uint_as_float(uu & 0xFFFF0000u);
            }
        }
        float2 b = ((const float2*)bias)[lane];
        float rx = fmaxf(ax * dd + b.x, 0.f);
        float ry = fmaxf(ay * dd + b.y, 0.f);
        unsigned pk = ((unsigned)f2bf(ry) << 16) | (unsigned)f2bf(rx);
        ((unsigned*)aggb)[(size_t)d * 64 + lane] = pk;
    } else {  // F == 64
        float acc = __uint_as_float((unsigned)hws[(size_t)d * 64 + lane] << 16);
        for (int e0 = beg; e0 < end; e0 += 64) {
            int nid = (e0 + lane < end) ? col[e0 + lane] : 0;
            int cnt = min(64, end - e0);
            int j = 0;
            for (; j + 8 <= cnt; j += 8) {
                ushort_t u[8];
#pragma unroll
                for (int q = 0; q < 8; ++q) {
                    int s = __shfl(nid, j + q);
                    u[q] = hws[(size_t)s * 64 + lane];
                }
#pragma unroll
                for (int q = 0; q < 8; ++q) acc += __uint_as_float((unsigned)u[q] << 16);
            }
            for (; j < cnt; ++j) {
                int s = __shfl(nid, j);
                acc += __uint_as_float((unsigned)hws[(size_t)s * 64 + lane] << 16);
            }
        }
        acc = fmaxf(acc * dd + bias[lane], 0.f);
        aggb[(size_t)d * 64 + lane] = f2bf(acc);
    }
}

// ---------------- edge decode (bf16 emb1 copy) ------------------------------
__global__ __launch_bounds__(256) void decode_kernel(const ushort_t* __restrict__ emb1b,
                                                     const int* __restrict__ eli,
                                                     const float* __restrict__ Wpost,
                                                     const float* __restrict__ bpost,
                                                     float* __restrict__ pred, int L) {
    const int wave = threadIdx.x >> 6;
    const int lane = threadIdx.x & 63;
    const int l = blockIdx.x * 4 + wave;
    if (l >= L) return;
    int s = eli[l];
    int d = eli[L + l];
    float w = Wpost[lane * 2] + Wpost[lane * 2 + 1];
    float a = __uint_as_float((unsigned)emb1b[(size_t)s * 64 + lane] << 16);
    float b = __uint_as_float((unsigned)emb1b[(size_t)d * 64 + lane] << 16);
    float p = a * b * w;
#pragma unroll
    for (int off = 32; off; off >>= 1) p += __shfl_down(p, off);
    if (lane == 0) pred[l] = p + bpost[0] + bpost[1];
}

// ---------------------------------------------------------------------------
extern "C" void kernel_launch(void* const* d_in, const int* in_sizes, int n_in,
                              void* d_out, int out_size, void* d_ws, size_t ws_size,
                              hipStream_t stream) {
    const float* x     = (const float*)d_in[0];
    const float* prev0 = (const float*)d_in[1];
    const float* prev1 = (const float*)d_in[2];
    const float* Wpre1 = (const float*)d_in[3];
    const float* bpre1 = (const float*)d_in[4];
    const float* Wpre2 = (const float*)d_in[5];
    const float* bpre2 = (const float*)d_in[6];
    const float* Wc1   = (const float*)d_in[7];
    const float* bc1   = (const float*)d_in[8];
    const float* Wc2   = (const float*)d_in[9];
    const float* bc2   = (const float*)d_in[10];
    const float* Wm1   = (const float*)d_in[11];
    const float* bm1   = (const float*)d_in[12];
    const float* Wm2   = (const float*)d_in[13];
    const float* bm2   = (const float*)d_in[14];
    const float* Wpost = (const float*)d_in[15];
    const float* bpost = (const float*)d_in[16];
    const int* edge_index = (const int*)d_in[17];
    const int* eli        = (const int*)d_in[18];

    const int N = in_sizes[0] / 256;   // 50000  (must be <= 65536 for packing)
    const int E = in_sizes[17] / 2;    // 1.6M
    const int L = in_sizes[18] / 2;    // 200K
    const int NB = (N + 255) >> BSHIFT;

    const int* src = edge_index;
    const int* dst = edge_index + E;

    float* out  = (float*)d_out;
    float* pred = out;                        // [L]
    float* emb0 = out + L;                    // [N,128]
    float* emb1 = out + L + (size_t)N * 128;  // [N,64]

    // ---- workspace layout (float slots); all regions disjoint in time ----
    // h1h   [0,128N)   (G1->G2)
    // h2b   [128N,192N) (G2->G3)
    // hws1b [0,64N)    (G3->gather1)      agg1b [64N,128N) (gather1->G5)
    // emb0b [0,64N)    (G5->G6)           hws2b [64N,96N)  (G6->gather2)
    // agg2b [96N,128N) (gather2->G8)      emb1b [0,32N)    (G8->decode)
    // tail @192N: packed[E] (build only), col[E], rowstart, dinv, buckets, wb
    float* ws = (float*)d_ws;
    ushort_t* h1h   = (ushort_t*)ws;
    ushort_t* hws1b = (ushort_t*)ws;
    ushort_t* emb0b = (ushort_t*)ws;
    ushort_t* emb1b = (ushort_t*)ws;
    ushort_t* agg1b = (ushort_t*)(ws + (size_t)64 * N);
    ushort_t* hws2b = (ushort_t*)(ws + (size_t)64 * N);
    ushort_t* agg2b = (ushort_t*)(ws + (size_t)96 * N);
    ushort_t* h2b   = (ushort_t*)(ws + (size_t)128 * N);

    size_t o = (size_t)192 * N;
    unsigned* packed = (unsigned*)(ws + o); o += ((size_t)E + 3) & ~(size_t)3;
    int* col = (int*)(ws + o);              o += ((size_t)E + 3) & ~(size_t)3;
    int* rowstart = (int*)(ws + o);         o += ((size_t)N + 4) & ~(size_t)3;
    float* dinv = ws + o;                   o += ((size_t)N + 3) & ~(size_t)3;
    int* bbase = (int*)(ws + o);            o += 260;
    int* bcursor = (int*)(ws + o);          o += 260;
    int* bcount = (int*)(ws + o);           o += 260;
    ushort_t* wb = (ushort_t*)(ws + o);     // 327680 ushorts (16B-aligned)

    ushort_t* wpre1h = wb + 0;       ushort_t* wpre1l = wb + 65536;
    ushort_t* wpre2h = wb + 131072;  ushort_t* wpre2l = wb + 163840;
    ushort_t* wc1h   = wb + 196608;  ushort_t* wc1l   = wb + 212992;
    ushort_t* wm1h   = wb + 229376;  ushort_t* wm1l   = wb + 262144;
    ushort_t* wc2h   = wb + 294912;  ushort_t* wc2l   = wb + 303104;
    ushort_t* wm2h   = wb + 311296;  ushort_t* wm2l   = wb + 319488;

    // 0) bucketed CSR build + dinv
    hipMemsetAsync(bcount, 0, (size_t)NB * sizeof(int), stream);
    bcount_kernel<<<1024, 256, 0, stream>>>(dst, bcount, E, NB);
    bscan_kernel<<<1, 256, 0, stream>>>(bcount, bbase, bcursor, NB, E);
    bpart_kernel<<<(E + 8191) / 8192, 256, 0, stream>>>(src, dst, bcursor, packed, E, NB);
    bbuild_kernel<<<NB, 256, 0, stream>>>(bbase, packed, col, rowstart, dinv, N, E);

    // 0b) weights: transpose + hi/lo split
    WAll wa;
    wa.d[0] = {Wpre1, wpre1h, wpre1l, 256, 256};
    wa.d[1] = {Wpre2, wpre2h, wpre2l, 256, 128};
    wa.d[2] = {Wc1,   wc1h,   wc1l,   128, 128};
    wa.d[3] = {Wm1,   wm1h,   wm1l,   256, 128};
    wa.d[4] = {Wc2,   wc2h,   wc2l,   128, 64};
    wa.d[5] = {Wm2,   wm2h,   wm2l,   128, 64};
    wtcvt_kernel<<<dim3(256, 6), 256, 0, stream>>>(wa);

    const int gt = (N + 31) / 32;   // 1563 row-tiles

    // 1) h1 = bf16(relu(x@Wpre1+b))           [N,256]  K=256, fp32 A
    gemm_reg<4, 256, 256, true, false, false, false, 2><<<gt, 256, 0, stream>>>(
        x, nullptr, nullptr, wpre1h, wpre1l, bpre1, nullptr, nullptr, h1h, N, 256);
    // 2) h2 = bf16(relu(h1@Wpre2+b))          [N,128]  K=256, bf16 A
    gemm_reg<2, 256, 256, true, false, false, true, 2><<<gt, 256, 0, stream>>>(
        nullptr, h1h, nullptr, wpre2h, wpre2l, bpre2, nullptr, nullptr, h2b, N, 128);
    // 3) hws1 = bf16((h2@Wc1)*dinv[row])      [N,128]  K=128  (h1 dead)
    gemm_reg<2, 128, 128, false, true, false, true, 2><<<gt, 256, 0, stream>>>(
        nullptr, h2b, nullptr, wc1h, wc1l, nullptr, dinv, nullptr, hws1b, N, 128);
    // 4) agg1 = bf16(relu(dinv*(hws1[d]+sum hws1[s])+bc1))
    gather_bf_kernel<128><<<(N + 3) / 4, 256, 0, stream>>>(rowstart, col, dinv, hws1b, bc1, agg1b, N);
    // 5) emb0 = [agg1,prev0]@Wm1+bm1 (fp32 + bf16 copy)  [N,128]  K=128+128
    gemm_reg<2, 256, 128, false, false, true, true, 3><<<gt, 256, 0, stream>>>(
        nullptr, agg1b, prev0, wm1h, wm1l, bm1, nullptr, emb0, emb0b, N, 128);
    // 6) hws2 = bf16((emb0@Wc2)*dinv[row])    [N,64]   K=128, bf16 A
    gemm_reg<1, 128, 128, false, true, false, true, 2><<<gt, 256, 0, stream>>>(
        nullptr, emb0b, nullptr, wc2h, wc2l, nullptr, dinv, nullptr, hws2b, N, 64);
    // 7) agg2 = bf16(relu(dinv*(hws2[d]+sum hws2[s])+bc2))
    gather_bf_kernel<64><<<(N + 3) / 4, 256, 0, stream>>>(rowstart, col, dinv, hws2b, bc2, agg2b, N);
    // 8) emb1 = [agg2,prev1]@Wm2+bm2 (fp32 + bf16 copy)  [N,64]  K=64+64
    gemm_reg<1, 128, 64, false, false, true, true, 3><<<gt, 256, 0, stream>>>(
        nullptr, agg2b, prev1, wm2h, wm2l, bm2, nullptr, emb1, emb1b, N, 64);
    // 9) decode (bf16 emb1 copy, L2-resident)
    decode_kernel<<<(L + 3) / 4, 256, 0, stream>>>(emb1b, eli, Wpost, bpost, pred, L);
}

// Round 11
// 373.813 us; speedup vs baseline: 1.2167x; 1.2167x over previous
//
#include <hip/hip_runtime.h>
#include <hip/hip_bf16.h>

// ---------------------------------------------------------------------------
// ROLAND-style GNN forward. Round 10: fragment-major weight layout -- each
// MFMA B-fragment (16 cols x 32 k) stored as one contiguous 1KB lane-indexed
// block, so every B-load is a fully coalesced dwordx4 (was a 16-way 64B
// scatter that serialized the TA and thrashed L1). Register-only streaming
// GEMM otherwise unchanged. Bucketed CSR build; bf16 CSR gather, 8-deep ILP.
// ---------------------------------------------------------------------------

typedef unsigned short ushort_t;
typedef __attribute__((ext_vector_type(8))) short s8v;   // 8 bf16 (4 VGPRs)
typedef __attribute__((ext_vector_type(4))) float f4;    // MFMA accumulator

#define BSHIFT 8                       // nodes per bucket = 256 (N<=65536)

__device__ __forceinline__ void bsplit(float v, ushort_t& hi, ushort_t& lo) {
    unsigned u = __float_as_uint(v);
    unsigned rh = u + 0x7FFFu + ((u >> 16) & 1u);
    hi = (ushort_t)(rh >> 16);
    float fh = __uint_as_float((unsigned)hi << 16);
    float d = v - fh;
    unsigned u2 = __float_as_uint(d);
    unsigned rl = u2 + 0x7FFFu + ((u2 >> 16) & 1u);
    lo = (ushort_t)(rl >> 16);
}

__device__ __forceinline__ ushort_t f2bf(float v) {
    unsigned u = __float_as_uint(v);
    return (ushort_t)((u + 0x7FFFu + ((u >> 16) & 1u)) >> 16);
}

__device__ __forceinline__ s8v cvt8(f4 v0, f4 v1) {
    ushort_t hb[8];
    hb[0] = f2bf(v0.x); hb[1] = f2bf(v0.y); hb[2] = f2bf(v0.z); hb[3] = f2bf(v0.w);
    hb[4] = f2bf(v1.x); hb[5] = f2bf(v1.y); hb[6] = f2bf(v1.z); hb[7] = f2bf(v1.w);
    return *(s8v*)hb;
}

// ---------------- register-only streaming MFMA GEMM -------------------------
// C[M,Nout] = epilogue( A[M,K1] (++ A2[M,KW-K1]) @ W[KW,Nout] )
// grid.x = ceil(M/32); block = 4 waves, wave w = column panel w (NT*16 cols).
// Wth/Wtl are FRAGMENT-MAJOR: ((colTile*(KW/32)+ks)*64+lane)*8+j.
// A1BF: A1 is bf16. OUTMODE: 0 = fp32, 2 = bf16, 3 = fp32 + bf16 copy.
template <int NT, int KW, int K1, bool RELU, bool SCALE, bool DUAL, bool A1BF, int OUTMODE>
__global__ __launch_bounds__(256, 3) void gemm_reg(
    const float* __restrict__ A1f, const ushort_t* __restrict__ A1h,
    const float* __restrict__ A2f,
    const ushort_t* __restrict__ Wth, const ushort_t* __restrict__ Wtl,
    const float* __restrict__ bias, const float* __restrict__ rowscale,
    float* __restrict__ Cf, ushort_t* __restrict__ Ch,
    int M, int Nout)
{
    constexpr int K2 = KW - K1;
    constexpr int KS = KW / 32;            // k-steps
    const int lane  = threadIdx.x & 63;
    const int w     = threadIdx.x >> 6;
    const int rbase = blockIdx.x * 32;
    const int bn    = w * (NT * 16);
    if (rbase >= M) return;

    f4 acc[2][NT];
    const f4 zero = {0.f, 0.f, 0.f, 0.f};
#pragma unroll
    for (int mi = 0; mi < 2; ++mi)
#pragma unroll
        for (int ni = 0; ni < NT; ++ni) acc[mi][ni] = zero;

    const int r0 = min(rbase + (lane & 15), M - 1);
    const int r1 = min(rbase + 16 + (lane & 15), M - 1);
    const int kq = (lane >> 4) * 8;        // k-offset of this lane's 8 elems

#pragma unroll
    for (int ks = 0; ks < KS; ++ks) {
        const int kb = ks * 32 + kq;
        // ---- A fragments (2 loads) ----
        s8v a0, a1;
        if (DUAL && ks * 32 >= K1) {
            const float* p0 = &A2f[(size_t)r0 * K2 + (kb - K1)];
            const float* p1 = &A2f[(size_t)r1 * K2 + (kb - K1)];
            a0 = cvt8(*(const f4*)p0, *(const f4*)(p0 + 4));
            a1 = cvt8(*(const f4*)p1, *(const f4*)(p1 + 4));
        } else if (A1BF) {
            a0 = *(const s8v*)&A1h[(size_t)r0 * K1 + kb];
            a1 = *(const s8v*)&A1h[(size_t)r1 * K1 + kb];
        } else {
            const float* p0 = &A1f[(size_t)r0 * K1 + kb];
            const float* p1 = &A1f[(size_t)r1 * K1 + kb];
            a0 = cvt8(*(const f4*)p0, *(const f4*)(p0 + 4));
            a1 = cvt8(*(const f4*)p1, *(const f4*)(p1 + 4));
        }
        // ---- B fragments: coalesced 1KB frag-major loads ----
        s8v bh[NT], bl[NT];
#pragma unroll
        for (int ni = 0; ni < NT; ++ni) {
            const size_t fo = (((size_t)((bn >> 4) + ni) * KS + ks) << 9) + ((size_t)lane << 3);
            bh[ni] = *(const s8v*)&Wth[fo];
            bl[ni] = *(const s8v*)&Wtl[fo];
        }
        // ---- MFMA cluster ----
#pragma unroll
        for (int ni = 0; ni < NT; ++ni) {
            acc[0][ni] = __builtin_amdgcn_mfma_f32_16x16x32_bf16(a0, bh[ni], acc[0][ni], 0, 0, 0);
            acc[0][ni] = __builtin_amdgcn_mfma_f32_16x16x32_bf16(a0, bl[ni], acc[0][ni], 0, 0, 0);
            acc[1][ni] = __builtin_amdgcn_mfma_f32_16x16x32_bf16(a1, bh[ni], acc[1][ni], 0, 0, 0);
            acc[1][ni] = __builtin_amdgcn_mfma_f32_16x16x32_bf16(a1, bl[ni], acc[1][ni], 0, 0, 0);
        }
    }

    // ---- epilogue: C/D layout col=lane&15, row=(lane>>4)*4+reg ----
#pragma unroll
    for (int mi = 0; mi < 2; ++mi) {
#pragma unroll
        for (int reg = 0; reg < 4; ++reg) {
            const int row = rbase + mi * 16 + (lane >> 4) * 4 + reg;
            if (row >= M) continue;
            const float rs = SCALE ? rowscale[row] : 1.f;
#pragma unroll
            for (int ni = 0; ni < NT; ++ni) {
                const int col = bn + ni * 16 + (lane & 15);
                float v = acc[mi][ni][reg];
                if (SCALE) v *= rs;
                if (bias) v += bias[col];
                if (RELU) v = fmaxf(v, 0.f);
                if constexpr (OUTMODE == 2) {
                    Ch[(size_t)row * Nout + col] = f2bf(v);
                } else if constexpr (OUTMODE == 3) {
                    Cf[(size_t)row * Nout + col] = v;
                    Ch[(size_t)row * Nout + col] = f2bf(v);
                } else {
                    Cf[(size_t)row * Nout + col] = v;
                }
            }
        }
    }
}

// ---------------- weight transpose + split (fragment-major) -----------------
struct WDesc { const float* W; ushort_t* h; ushort_t* l; int K; int No; };
struct WAll { WDesc d[6]; };

__global__ void wtcvt_kernel(WAll wa) {
    WDesc d = wa.d[blockIdx.y];
    int e = blockIdx.x * blockDim.x + threadIdx.x;
    if (e >= d.K * d.No) return;
    int k = e / d.No, n = e - k * d.No;
    ushort_t h, l;
    bsplit(d.W[e], h, l);
    int colTile = n >> 4, c16 = n & 15;
    int ks = k >> 5, quad = (k >> 3) & 3, j = k & 7;
    int lane = c16 + (quad << 4);
    size_t idx = (((size_t)colTile * (d.K >> 5) + ks) << 9) + ((size_t)lane << 3) + j;
    d.h[idx] = h;
    d.l[idx] = l;
}

// ---------------- bucketed CSR build ----------------------------------------
__global__ __launch_bounds__(256) void bcount_kernel(const int* __restrict__ dst,
                                                     int* __restrict__ bcount, int E, int NB) {
    __shared__ int cnt[256];
    const int t = threadIdx.x;
    if (t < NB) cnt[t] = 0;
    __syncthreads();
    for (int e = blockIdx.x * 256 + t; e < E; e += gridDim.x * 256)
        atomicAdd(&cnt[dst[e] >> BSHIFT], 1);
    __syncthreads();
    if (t < NB && cnt[t]) atomicAdd(&bcount[t], cnt[t]);
}

__global__ __launch_bounds__(256) void bscan_kernel(const int* __restrict__ bcount,
                                                    int* __restrict__ bbase,
                                                    int* __restrict__ bcursor, int NB, int E) {
    __shared__ int s[256];
    const int t = threadIdx.x;
    s[t] = (t < NB) ? bcount[t] : 0;
    __syncthreads();
    for (int off = 1; off < 256; off <<= 1) {
        int v = (t >= off) ? s[t - off] : 0;
        __syncthreads();
        s[t] += v;
        __syncthreads();
    }
    int excl = t ? s[t - 1] : 0;
    if (t < NB) { bbase[t] = excl; bcursor[t] = excl; }
    if (t == 0) bbase[NB] = E;
}

__global__ __launch_bounds__(256) void bpart_kernel(const int* __restrict__ src,
                                                    const int* __restrict__ dst,
                                                    int* __restrict__ bcursor,
                                                    unsigned* __restrict__ packed, int E, int NB) {
    __shared__ int cnt[256];
    __shared__ int cur[256];
    const int t = threadIdx.x;
    const int beg = blockIdx.x * 8192;
    const int end = min(beg + 8192, E);
    if (t < NB) cnt[t] = 0;
    __syncthreads();
    for (int e = beg + t; e < end; e += 256) atomicAdd(&cnt[dst[e] >> BSHIFT], 1);
    __syncthreads();
    if (t < NB && cnt[t]) cur[t] = atomicAdd(&bcursor[t], cnt[t]);
    __syncthreads();
    for (int e = beg + t; e < end; e += 256) {
        int d = dst[e];
        int b = d >> BSHIFT;
        int pos = atomicAdd(&cur[b], 1);
        packed[pos] = (unsigned)src[e] | ((unsigned)(d & ((1 << BSHIFT) - 1)) << 16);
    }
}

__global__ __launch_bounds__(256) void bbuild_kernel(const int* __restrict__ bbase,
                                                     const unsigned* __restrict__ packed,
                                                     int* __restrict__ col,
                                                     int* __restrict__ rowstart,
                                                     float* __restrict__ dinv, int N, int E) {
    __shared__ int ncnt[256];
    __shared__ int s[256];
    __shared__ int ncur[256];
    const int b = blockIdx.x;
    const int t = threadIdx.x;
    const int beg = bbase[b], end = bbase[b + 1];
    const int node0 = b << BSHIFT;
    const int nInB = min(256, N - node0);
    ncnt[t] = 0;
    __syncthreads();
    for (int e = beg + t; e < end; e += 256) atomicAdd(&ncnt[packed[e] >> 16], 1);
    __syncthreads();
    s[t] = ncnt[t];
    __syncthreads();
    for (int off = 1; off < 256; off <<= 1) {
        int v = (t >= off) ? s[t - off] : 0;
        __syncthreads();
        s[t] += v;
        __syncthreads();
    }
    int excl = t ? s[t - 1] : 0;
    if (t < nInB) {
        rowstart[node0 + t] = beg + excl;
        dinv[node0 + t] = rsqrtf((float)ncnt[t] + 1.0f);
    }
    ncur[t] = beg + excl;
    __syncthreads();
    for (int e = beg + t; e < end; e += 256) {
        unsigned p = packed[e];
        int pos = atomicAdd(&ncur[p >> 16], 1);
        col[pos] = (int)(p & 0xFFFFu);
    }
    if (b == 0 && t == 0) rowstart[N] = E;
}

// ---------------- CSR gather (bf16 in, bf16 out, 8-deep ILP) ----------------
template <int F>
__global__ __launch_bounds__(256) void gather_bf_kernel(const int* __restrict__ rowstart,
                                                        const int* __restrict__ col,
                                                        const float* __restrict__ dinv,
                                                        const ushort_t* __restrict__ hws,
                                                        const float* __restrict__ bias,
                                                        ushort_t* __restrict__ aggb, int N) {
    const int wave = threadIdx.x >> 6;
    const int lane = threadIdx.x & 63;
    const int d = blockIdx.x * 4 + wave;
    if (d >= N) return;
    const int beg = rowstart[d], end = rowstart[d + 1];
    const float dd = dinv[d];
    if (F == 128) {
        const unsigned* base = (const unsigned*)hws;   // 2 bf16 per uint
        unsigned sv = base[(size_t)d * 64 + lane];
        float ax = __uint_as_float(sv << 16);
        float ay = __uint_as_float(sv & 0xFFFF0000u);
        for (int e0 = beg; e0 < end; e0 += 64) {
            int nid = (e0 + lane < end) ? col[e0 + lane] : 0;
            int cnt = min(64, end - e0);
            int j = 0;
            for (; j + 8 <= cnt; j += 8) {
                unsigned u[8];
#pragma unroll
                for (int q = 0; q < 8; ++q) {
                    int s = __shfl(nid, j + q);
                    u[q] = base[(size_t)s * 64 + lane];
                }
#pragma unroll
                for (int q = 0; q < 8; ++q) {
                    ax += __uint_as_float(u[q] << 16);
                    ay += __uint_as_float(u[q] & 0xFFFF0000u);
                }
            }
            for (; j < cnt; ++j) {
                int s = __shfl(nid, j);
                unsigned uu = base[(size_t)s * 64 + lane];
                ax += __uint_as_float(uu << 16);
                ay += __uint_as_float(uu & 0xFFFF0000u);
            }
        }
        float2 b = ((const float2*)bias)[lane];
        float rx = fmaxf(ax * dd + b.x, 0.f);
        float ry = fmaxf(ay * dd + b.y, 0.f);
        unsigned pk = ((unsigned)f2bf(ry) << 16) | (unsigned)f2bf(rx);
        ((unsigned*)aggb)[(size_t)d * 64 + lane] = pk;
    } else {  // F == 64
        float acc = __uint_as_float((unsigned)hws[(size_t)d * 64 + lane] << 16);
        for (int e0 = beg; e0 < end; e0 += 64) {
            int nid = (e0 + lane < end) ? col[e0 + lane] : 0;
            int cnt = min(64, end - e0);
            int j = 0;
            for (; j + 8 <= cnt; j += 8) {
                ushort_t u[8];
#pragma unroll
                for (int q = 0; q < 8; ++q) {
                    int s = __shfl(nid, j + q);
                    u[q] = hws[(size_t)s * 64 + lane];
                }
#pragma unroll
                for (int q = 0; q < 8; ++q) acc += __uint_as_float((unsigned)u[q] << 16);
            }
            for (; j < cnt; ++j) {
                int s = __shfl(nid, j);
                acc += __uint_as_float((unsigned)hws[(size_t)s * 64 + lane] << 16);
            }
        }
        acc = fmaxf(acc * dd + bias[lane], 0.f);
        aggb[(size_t)d * 64 + lane] = f2bf(acc);
    }
}

// ---------------- edge decode (bf16 emb1 copy) ------------------------------
__global__ __launch_bounds__(256) void decode_kernel(const ushort_t* __restrict__ emb1b,
                                                     const int* __restrict__ eli,
                                                     const float* __restrict__ Wpost,
                                                     const float* __restrict__ bpost,
                                                     float* __restrict__ pred, int L) {
    const int wave = threadIdx.x >> 6;
    const int lane = threadIdx.x & 63;
    const int l = blockIdx.x * 4 + wave;
    if (l >= L) return;
    int s = eli[l];
    int d = eli[L + l];
    float w = Wpost[lane * 2] + Wpost[lane * 2 + 1];
    float a = __uint_as_float((unsigned)emb1b[(size_t)s * 64 + lane] << 16);
    float b = __uint_as_float((unsigned)emb1b[(size_t)d * 64 + lane] << 16);
    float p = a * b * w;
#pragma unroll
    for (int off = 32; off; off >>= 1) p += __shfl_down(p, off);
    if (lane == 0) pred[l] = p + bpost[0] + bpost[1];
}

// ---------------------------------------------------------------------------
extern "C" void kernel_launch(void* const* d_in, const int* in_sizes, int n_in,
                              void* d_out, int out_size, void* d_ws, size_t ws_size,
                              hipStream_t stream) {
    const float* x     = (const float*)d_in[0];
    const float* prev0 = (const float*)d_in[1];
    const float* prev1 = (const float*)d_in[2];
    const float* Wpre1 = (const float*)d_in[3];
    const float* bpre1 = (const float*)d_in[4];
    const float* Wpre2 = (const float*)d_in[5];
    const float* bpre2 = (const float*)d_in[6];
    const float* Wc1   = (const float*)d_in[7];
    const float* bc1   = (const float*)d_in[8];
    const float* Wc2   = (const float*)d_in[9];
    const float* bc2   = (const float*)d_in[10];
    const float* Wm1   = (const float*)d_in[11];
    const float* bm1   = (const float*)d_in[12];
    const float* Wm2   = (const float*)d_in[13];
    const float* bm2   = (const float*)d_in[14];
    const float* Wpost = (const float*)d_in[15];
    const float* bpost = (const float*)d_in[16];
    const int* edge_index = (const int*)d_in[17];
    const int* eli        = (const int*)d_in[18];

    const int N = in_sizes[0] / 256;   // 50000  (must be <= 65536 for packing)
    const int E = in_sizes[17] / 2;    // 1.6M
    const int L = in_sizes[18] / 2;    // 200K
    const int NB = (N + 255) >> BSHIFT;

    const int* src = edge_index;
    const int* dst = edge_index + E;

    float* out  = (float*)d_out;
    float* pred = out;                        // [L]
    float* emb0 = out + L;                    // [N,128]
    float* emb1 = out + L + (size_t)N * 128;  // [N,64]

    // ---- workspace layout (float slots); all regions disjoint in time ----
    float* ws = (float*)d_ws;
    ushort_t* h1h   = (ushort_t*)ws;                       // [0,128N)
    ushort_t* hws1b = (ushort_t*)ws;                       // [0,64N)
    ushort_t* emb0b = (ushort_t*)ws;                       // [0,64N)
    ushort_t* emb1b = (ushort_t*)ws;                       // [0,32N)
    ushort_t* agg1b = (ushort_t*)(ws + (size_t)64 * N);    // [64N,128N)
    ushort_t* hws2b = (ushort_t*)(ws + (size_t)64 * N);    // [64N,96N)
    ushort_t* agg2b = (ushort_t*)(ws + (size_t)96 * N);    // [96N,128N)
    ushort_t* h2b   = (ushort_t*)(ws + (size_t)128 * N);   // [128N,192N)

    size_t o = (size_t)192 * N;
    unsigned* packed = (unsigned*)(ws + o); o += ((size_t)E + 3) & ~(size_t)3;
    int* col = (int*)(ws + o);              o += ((size_t)E + 3) & ~(size_t)3;
    int* rowstart = (int*)(ws + o);         o += ((size_t)N + 4) & ~(size_t)3;
    float* dinv = ws + o;                   o += ((size_t)N + 3) & ~(size_t)3;
    int* bbase = (int*)(ws + o);            o += 260;
    int* bcursor = (int*)(ws + o);          o += 260;
    int* bcount = (int*)(ws + o);           o += 260;
    ushort_t* wb = (ushort_t*)(ws + o);     // 327680 ushorts (16B-aligned)

    ushort_t* wpre1h = wb + 0;       ushort_t* wpre1l = wb + 65536;
    ushort_t* wpre2h = wb + 131072;  ushort_t* wpre2l = wb + 163840;
    ushort_t* wc1h   = wb + 196608;  ushort_t* wc1l   = wb + 212992;
    ushort_t* wm1h   = wb + 229376;  ushort_t* wm1l   = wb + 262144;
    ushort_t* wc2h   = wb + 294912;  ushort_t* wc2l   = wb + 303104;
    ushort_t* wm2h   = wb + 311296;  ushort_t* wm2l   = wb + 319488;

    // 0) bucketed CSR build + dinv
    hipMemsetAsync(bcount, 0, (size_t)NB * sizeof(int), stream);
    bcount_kernel<<<1024, 256, 0, stream>>>(dst, bcount, E, NB);
    bscan_kernel<<<1, 256, 0, stream>>>(bcount, bbase, bcursor, NB, E);
    bpart_kernel<<<(E + 8191) / 8192, 256, 0, stream>>>(src, dst, bcursor, packed, E, NB);
    bbuild_kernel<<<NB, 256, 0, stream>>>(bbase, packed, col, rowstart, dinv, N, E);

    // 0b) weights: transpose + hi/lo split into fragment-major layout
    WAll wa;
    wa.d[0] = {Wpre1, wpre1h, wpre1l, 256, 256};
    wa.d[1] = {Wpre2, wpre2h, wpre2l, 256, 128};
    wa.d[2] = {Wc1,   wc1h,   wc1l,   128, 128};
    wa.d[3] = {Wm1,   wm1h,   wm1l,   256, 128};
    wa.d[4] = {Wc2,   wc2h,   wc2l,   128, 64};
    wa.d[5] = {Wm2,   wm2h,   wm2l,   128, 64};
    wtcvt_kernel<<<dim3(256, 6), 256, 0, stream>>>(wa);

    const int gt = (N + 31) / 32;   // 1563 row-tiles

    // 1) h1 = bf16(relu(x@Wpre1+b))           [N,256]  K=256, fp32 A
    gemm_reg<4, 256, 256, true, false, false, false, 2><<<gt, 256, 0, stream>>>(
        x, nullptr, nullptr, wpre1h, wpre1l, bpre1, nullptr, nullptr, h1h, N, 256);
    // 2) h2 = bf16(relu(h1@Wpre2+b))          [N,128]  K=256, bf16 A
    gemm_reg<2, 256, 256, true, false, false, true, 2><<<gt, 256, 0, stream>>>(
        nullptr, h1h, nullptr, wpre2h, wpre2l, bpre2, nullptr, nullptr, h2b, N, 128);
    // 3) hws1 = bf16((h2@Wc1)*dinv[row])      [N,128]  K=128  (h1 dead)
    gemm_reg<2, 128, 128, false, true, false, true, 2><<<gt, 256, 0, stream>>>(
        nullptr, h2b, nullptr, wc1h, wc1l, nullptr, dinv, nullptr, hws1b, N, 128);
    // 4) agg1 = bf16(relu(dinv*(hws1[d]+sum hws1[s])+bc1))
    gather_bf_kernel<128><<<(N + 3) / 4, 256, 0, stream>>>(rowstart, col, dinv, hws1b, bc1, agg1b, N);
    // 5) emb0 = [agg1,prev0]@Wm1+bm1 (fp32 + bf16 copy)  [N,128]  K=128+128
    gemm_reg<2, 256, 128, false, false, true, true, 3><<<gt, 256, 0, stream>>>(
        nullptr, agg1b, prev0, wm1h, wm1l, bm1, nullptr, emb0, emb0b, N, 128);
    // 6) hws2 = bf16((emb0@Wc2)*dinv[row])    [N,64]   K=128, bf16 A
    gemm_reg<1, 128, 128, false, true, false, true, 2><<<gt, 256, 0, stream>>>(
        nullptr, emb0b, nullptr, wc2h, wc2l, nullptr, dinv, nullptr, hws2b, N, 64);
    // 7) agg2 = bf16(relu(dinv*(hws2[d]+sum hws2[s])+bc2))
    gather_bf_kernel<64><<<(N + 3) / 4, 256, 0, stream>>>(rowstart, col, dinv, hws2b, bc2, agg2b, N);
    // 8) emb1 = [agg2,prev1]@Wm2+bm2 (fp32 + bf16 copy)  [N,64]  K=64+64
    gemm_reg<1, 128, 64, false, false, true, true, 3><<<gt, 256, 0, stream>>>(
        nullptr, agg2b, prev1, wm2h, wm2l, bm2, nullptr, emb1, emb1b, N, 64);
    // 9) decode (bf16 emb1 copy, L2-resident)
    decode_kernel<<<(L + 3) / 4, 256, 0, stream>>>(emb1b, eli, Wpost, bpost, pred, L);
}

// Round 12
// 366.243 us; speedup vs baseline: 1.2419x; 1.0207x over previous
//
#include <hip/hip_runtime.h>
#include <hip/hip_bf16.h>

// ---------------------------------------------------------------------------
// ROLAND-style GNN forward. Round 11: explicit two-set register double-buffer
// in gemm_reg's k-loop -- named A/B fragment sets force the compiler to keep
// ~10 loads in flight per wave (round-10's VGPR=40 showed it was serializing
// load->wait->MFMA). Frag-major weights; register-only streaming GEMM;
// bucketed CSR build; bf16 CSR gather with 8-deep ILP.
// ---------------------------------------------------------------------------

typedef unsigned short ushort_t;
typedef __attribute__((ext_vector_type(8))) short s8v;   // 8 bf16 (4 VGPRs)
typedef __attribute__((ext_vector_type(4))) float f4;    // MFMA accumulator

#define BSHIFT 8                       // nodes per bucket = 256 (N<=65536)

__device__ __forceinline__ void bsplit(float v, ushort_t& hi, ushort_t& lo) {
    unsigned u = __float_as_uint(v);
    unsigned rh = u + 0x7FFFu + ((u >> 16) & 1u);
    hi = (ushort_t)(rh >> 16);
    float fh = __uint_as_float((unsigned)hi << 16);
    float d = v - fh;
    unsigned u2 = __float_as_uint(d);
    unsigned rl = u2 + 0x7FFFu + ((u2 >> 16) & 1u);
    lo = (ushort_t)(rl >> 16);
}

__device__ __forceinline__ ushort_t f2bf(float v) {
    unsigned u = __float_as_uint(v);
    return (ushort_t)((u + 0x7FFFu + ((u >> 16) & 1u)) >> 16);
}

__device__ __forceinline__ s8v cvt8(f4 v0, f4 v1) {
    ushort_t hb[8];
    hb[0] = f2bf(v0.x); hb[1] = f2bf(v0.y); hb[2] = f2bf(v0.z); hb[3] = f2bf(v0.w);
    hb[4] = f2bf(v1.x); hb[5] = f2bf(v1.y); hb[6] = f2bf(v1.z); hb[7] = f2bf(v1.w);
    return *(s8v*)hb;
}

// ---------------- register-only streaming MFMA GEMM (reg-dbuf) --------------
// C[M,Nout] = epilogue( A[M,K1] (++ A2[M,KW-K1]) @ W[KW,Nout] )
// grid.x = ceil(M/32); block = 4 waves, wave w = column panel w (NT*16 cols).
// Wth/Wtl are FRAGMENT-MAJOR: ((colTile*(KW/32)+ks)*64+lane)*8+j.
// A1BF: A1 is bf16. OUTMODE: 0 = fp32, 2 = bf16, 3 = fp32 + bf16 copy.
template <int NT, int KW, int K1, bool RELU, bool SCALE, bool DUAL, bool A1BF, int OUTMODE>
__global__ __launch_bounds__(256, 3) void gemm_reg(
    const float* __restrict__ A1f, const ushort_t* __restrict__ A1h,
    const float* __restrict__ A2f,
    const ushort_t* __restrict__ Wth, const ushort_t* __restrict__ Wtl,
    const float* __restrict__ bias, const float* __restrict__ rowscale,
    float* __restrict__ Cf, ushort_t* __restrict__ Ch,
    int M, int Nout)
{
    constexpr int K2 = KW - K1;
    constexpr int KS = KW / 32;            // k-steps
    const int lane  = threadIdx.x & 63;
    const int w     = threadIdx.x >> 6;
    const int rbase = blockIdx.x * 32;
    const int bn    = w * (NT * 16);
    if (rbase >= M) return;

    f4 acc[2][NT];
    const f4 zero = {0.f, 0.f, 0.f, 0.f};
#pragma unroll
    for (int mi = 0; mi < 2; ++mi)
#pragma unroll
        for (int ni = 0; ni < NT; ++ni) acc[mi][ni] = zero;

    const int r0 = min(rbase + (lane & 15), M - 1);
    const int r1 = min(rbase + 16 + (lane & 15), M - 1);
    const int kq = (lane >> 4) * 8;        // k-offset of this lane's 8 elems

    // two named register sets (static indexing only)
    s8v a0A, a1A, bhA[NT], blA[NT];
    s8v a0B, a1B, bhB[NT], blB[NT];

    auto loadK = [&](int ks, s8v& a0, s8v& a1, s8v* bh, s8v* bl) {
        const int kb = ks * 32 + kq;
        if (DUAL && ks * 32 >= K1) {
            const float* p0 = &A2f[(size_t)r0 * K2 + (kb - K1)];
            const float* p1 = &A2f[(size_t)r1 * K2 + (kb - K1)];
            a0 = cvt8(*(const f4*)p0, *(const f4*)(p0 + 4));
            a1 = cvt8(*(const f4*)p1, *(const f4*)(p1 + 4));
        } else if (A1BF) {
            a0 = *(const s8v*)&A1h[(size_t)r0 * K1 + kb];
            a1 = *(const s8v*)&A1h[(size_t)r1 * K1 + kb];
        } else {
            const float* p0 = &A1f[(size_t)r0 * K1 + kb];
            const float* p1 = &A1f[(size_t)r1 * K1 + kb];
            a0 = cvt8(*(const f4*)p0, *(const f4*)(p0 + 4));
            a1 = cvt8(*(const f4*)p1, *(const f4*)(p1 + 4));
        }
#pragma unroll
        for (int ni = 0; ni < NT; ++ni) {
            const size_t fo = (((size_t)((bn >> 4) + ni) * KS + ks) << 9) + ((size_t)lane << 3);
            bh[ni] = *(const s8v*)&Wth[fo];
            bl[ni] = *(const s8v*)&Wtl[fo];
        }
    };
    auto mfmaK = [&](const s8v& a0, const s8v& a1, const s8v* bh, const s8v* bl) {
#pragma unroll
        for (int ni = 0; ni < NT; ++ni) {
            acc[0][ni] = __builtin_amdgcn_mfma_f32_16x16x32_bf16(a0, bh[ni], acc[0][ni], 0, 0, 0);
            acc[0][ni] = __builtin_amdgcn_mfma_f32_16x16x32_bf16(a0, bl[ni], acc[0][ni], 0, 0, 0);
            acc[1][ni] = __builtin_amdgcn_mfma_f32_16x16x32_bf16(a1, bh[ni], acc[1][ni], 0, 0, 0);
            acc[1][ni] = __builtin_amdgcn_mfma_f32_16x16x32_bf16(a1, bl[ni], acc[1][ni], 0, 0, 0);
        }
    };

    loadK(0, a0A, a1A, bhA, blA);
#pragma unroll
    for (int ks = 0; ks < KS; ++ks) {
        if ((ks & 1) == 0) {
            if (ks + 1 < KS) loadK(ks + 1, a0B, a1B, bhB, blB);   // prefetch into B set
            mfmaK(a0A, a1A, bhA, blA);                            // consume A set
        } else {
            if (ks + 1 < KS) loadK(ks + 1, a0A, a1A, bhA, blA);   // prefetch into A set
            mfmaK(a0B, a1B, bhB, blB);                            // consume B set
        }
    }

    // ---- epilogue: C/D layout col=lane&15, row=(lane>>4)*4+reg ----
#pragma unroll
    for (int mi = 0; mi < 2; ++mi) {
#pragma unroll
        for (int reg = 0; reg < 4; ++reg) {
            const int row = rbase + mi * 16 + (lane >> 4) * 4 + reg;
            if (row >= M) continue;
            const float rs = SCALE ? rowscale[row] : 1.f;
#pragma unroll
            for (int ni = 0; ni < NT; ++ni) {
                const int col = bn + ni * 16 + (lane & 15);
                float v = acc[mi][ni][reg];
                if (SCALE) v *= rs;
                if (bias) v += bias[col];
                if (RELU) v = fmaxf(v, 0.f);
                if constexpr (OUTMODE == 2) {
                    Ch[(size_t)row * Nout + col] = f2bf(v);
                } else if constexpr (OUTMODE == 3) {
                    Cf[(size_t)row * Nout + col] = v;
                    Ch[(size_t)row * Nout + col] = f2bf(v);
                } else {
                    Cf[(size_t)row * Nout + col] = v;
                }
            }
        }
    }
}

// ---------------- weight transpose + split (fragment-major) -----------------
struct WDesc { const float* W; ushort_t* h; ushort_t* l; int K; int No; };
struct WAll { WDesc d[6]; };

__global__ void wtcvt_kernel(WAll wa) {
    WDesc d = wa.d[blockIdx.y];
    int e = blockIdx.x * blockDim.x + threadIdx.x;
    if (e >= d.K * d.No) return;
    int k = e / d.No, n = e - k * d.No;
    ushort_t h, l;
    bsplit(d.W[e], h, l);
    int colTile = n >> 4, c16 = n & 15;
    int ks = k >> 5, quad = (k >> 3) & 3, j = k & 7;
    int lane = c16 + (quad << 4);
    size_t idx = (((size_t)colTile * (d.K >> 5) + ks) << 9) + ((size_t)lane << 3) + j;
    d.h[idx] = h;
    d.l[idx] = l;
}

// ---------------- bucketed CSR build ----------------------------------------
__global__ __launch_bounds__(256) void bcount_kernel(const int* __restrict__ dst,
                                                     int* __restrict__ bcount, int E, int NB) {
    __shared__ int cnt[256];
    const int t = threadIdx.x;
    if (t < NB) cnt[t] = 0;
    __syncthreads();
    for (int e = blockIdx.x * 256 + t; e < E; e += gridDim.x * 256)
        atomicAdd(&cnt[dst[e] >> BSHIFT], 1);
    __syncthreads();
    if (t < NB && cnt[t]) atomicAdd(&bcount[t], cnt[t]);
}

__global__ __launch_bounds__(256) void bscan_kernel(const int* __restrict__ bcount,
                                                    int* __restrict__ bbase,
                                                    int* __restrict__ bcursor, int NB, int E) {
    __shared__ int s[256];
    const int t = threadIdx.x;
    s[t] = (t < NB) ? bcount[t] : 0;
    __syncthreads();
    for (int off = 1; off < 256; off <<= 1) {
        int v = (t >= off) ? s[t - off] : 0;
        __syncthreads();
        s[t] += v;
        __syncthreads();
    }
    int excl = t ? s[t - 1] : 0;
    if (t < NB) { bbase[t] = excl; bcursor[t] = excl; }
    if (t == 0) bbase[NB] = E;
}

__global__ __launch_bounds__(256) void bpart_kernel(const int* __restrict__ src,
                                                    const int* __restrict__ dst,
                                                    int* __restrict__ bcursor,
                                                    unsigned* __restrict__ packed, int E, int NB) {
    __shared__ int cnt[256];
    __shared__ int cur[256];
    const int t = threadIdx.x;
    const int beg = blockIdx.x * 8192;
    const int end = min(beg + 8192, E);
    if (t < NB) cnt[t] = 0;
    __syncthreads();
    for (int e = beg + t; e < end; e += 256) atomicAdd(&cnt[dst[e] >> BSHIFT], 1);
    __syncthreads();
    if (t < NB && cnt[t]) cur[t] = atomicAdd(&bcursor[t], cnt[t]);
    __syncthreads();
    for (int e = beg + t; e < end; e += 256) {
        int d = dst[e];
        int b = d >> BSHIFT;
        int pos = atomicAdd(&cur[b], 1);
        packed[pos] = (unsigned)src[e] | ((unsigned)(d & ((1 << BSHIFT) - 1)) << 16);
    }
}

__global__ __launch_bounds__(256) void bbuild_kernel(const int* __restrict__ bbase,
                                                     const unsigned* __restrict__ packed,
                                                     int* __restrict__ col,
                                                     int* __restrict__ rowstart,
                                                     float* __restrict__ dinv, int N, int E) {
    __shared__ int ncnt[256];
    __shared__ int s[256];
    __shared__ int ncur[256];
    const int b = blockIdx.x;
    const int t = threadIdx.x;
    const int beg = bbase[b], end = bbase[b + 1];
    const int node0 = b << BSHIFT;
    const int nInB = min(256, N - node0);
    ncnt[t] = 0;
    __syncthreads();
    for (int e = beg + t; e < end; e += 256) atomicAdd(&ncnt[packed[e] >> 16], 1);
    __syncthreads();
    s[t] = ncnt[t];
    __syncthreads();
    for (int off = 1; off < 256; off <<= 1) {
        int v = (t >= off) ? s[t - off] : 0;
        __syncthreads();
        s[t] += v;
        __syncthreads();
    }
    int excl = t ? s[t - 1] : 0;
    if (t < nInB) {
        rowstart[node0 + t] = beg + excl;
        dinv[node0 + t] = rsqrtf((float)ncnt[t] + 1.0f);
    }
    ncur[t] = beg + excl;
    __syncthreads();
    for (int e = beg + t; e < end; e += 256) {
        unsigned p = packed[e];
        int pos = atomicAdd(&ncur[p >> 16], 1);
        col[pos] = (int)(p & 0xFFFFu);
    }
    if (b == 0 && t == 0) rowstart[N] = E;
}

// ---------------- CSR gather (bf16 in, bf16 out, 8-deep ILP) ----------------
template <int F>
__global__ __launch_bounds__(256) void gather_bf_kernel(const int* __restrict__ rowstart,
                                                        const int* __restrict__ col,
                                                        const float* __restrict__ dinv,
                                                        const ushort_t* __restrict__ hws,
                                                        const float* __restrict__ bias,
                                                        ushort_t* __restrict__ aggb, int N) {
    const int wave = threadIdx.x >> 6;
    const int lane = threadIdx.x & 63;
    const int d = blockIdx.x * 4 + wave;
    if (d >= N) return;
    const int beg = rowstart[d], end = rowstart[d + 1];
    const float dd = dinv[d];
    if (F == 128) {
        const unsigned* base = (const unsigned*)hws;   // 2 bf16 per uint
        unsigned sv = base[(size_t)d * 64 + lane];
        float ax = __uint_as_float(sv << 16);
        float ay = __uint_as_float(sv & 0xFFFF0000u);
        for (int e0 = beg; e0 < end; e0 += 64) {
            int nid = (e0 + lane < end) ? col[e0 + lane] : 0;
            int cnt = min(64, end - e0);
            int j = 0;
            for (; j + 8 <= cnt; j += 8) {
                unsigned u[8];
#pragma unroll
                for (int q = 0; q < 8; ++q) {
                    int s = __shfl(nid, j + q);
                    u[q] = base[(size_t)s * 64 + lane];
                }
#pragma unroll
                for (int q = 0; q < 8; ++q) {
                    ax += __uint_as_float(u[q] << 16);
                    ay += __uint_as_float(u[q] & 0xFFFF0000u);
                }
            }
            for (; j < cnt; ++j) {
                int s = __shfl(nid, j);
                unsigned uu = base[(size_t)s * 64 + lane];
                ax += __uint_as_float(uu << 16);
                ay += __uint_as_float(uu & 0xFFFF0000u);
            }
        }
        float2 b = ((const float2*)bias)[lane];
        float rx = fmaxf(ax * dd + b.x, 0.f);
        float ry = fmaxf(ay * dd + b.y, 0.f);
        unsigned pk = ((unsigned)f2bf(ry) << 16) | (unsigned)f2bf(rx);
        ((unsigned*)aggb)[(size_t)d * 64 + lane] = pk;
    } else {  // F == 64
        float acc = __uint_as_float((unsigned)hws[(size_t)d * 64 + lane] << 16);
        for (int e0 = beg; e0 < end; e0 += 64) {
            int nid = (e0 + lane < end) ? col[e0 + lane] : 0;
            int cnt = min(64, end - e0);
            int j = 0;
            for (; j + 8 <= cnt; j += 8) {
                ushort_t u[8];
#pragma unroll
                for (int q = 0; q < 8; ++q) {
                    int s = __shfl(nid, j + q);
                    u[q] = hws[(size_t)s * 64 + lane];
                }
#pragma unroll
                for (int q = 0; q < 8; ++q) acc += __uint_as_float((unsigned)u[q] << 16);
            }
            for (; j < cnt; ++j) {
                int s = __shfl(nid, j);
                acc += __uint_as_float((unsigned)hws[(size_t)s * 64 + lane] << 16);
            }
        }
        acc = fmaxf(acc * dd + bias[lane], 0.f);
        aggb[(size_t)d * 64 + lane] = f2bf(acc);
    }
}

// ---------------- edge decode (bf16 emb1 copy) ------------------------------
__global__ __launch_bounds__(256) void decode_kernel(const ushort_t* __restrict__ emb1b,
                                                     const int* __restrict__ eli,
                                                     const float* __restrict__ Wpost,
                                                     const float* __restrict__ bpost,
                                                     float* __restrict__ pred, int L) {
    const int wave = threadIdx.x >> 6;
    const int lane = threadIdx.x & 63;
    const int l = blockIdx.x * 4 + wave;
    if (l >= L) return;
    int s = eli[l];
    int d = eli[L + l];
    float w = Wpost[lane * 2] + Wpost[lane * 2 + 1];
    float a = __uint_as_float((unsigned)emb1b[(size_t)s * 64 + lane] << 16);
    float b = __uint_as_float((unsigned)emb1b[(size_t)d * 64 + lane] << 16);
    float p = a * b * w;
#pragma unroll
    for (int off = 32; off; off >>= 1) p += __shfl_down(p, off);
    if (lane == 0) pred[l] = p + bpost[0] + bpost[1];
}

// ---------------------------------------------------------------------------
extern "C" void kernel_launch(void* const* d_in, const int* in_sizes, int n_in,
                              void* d_out, int out_size, void* d_ws, size_t ws_size,
                              hipStream_t stream) {
    const float* x     = (const float*)d_in[0];
    const float* prev0 = (const float*)d_in[1];
    const float* prev1 = (const float*)d_in[2];
    const float* Wpre1 = (const float*)d_in[3];
    const float* bpre1 = (const float*)d_in[4];
    const float* Wpre2 = (const float*)d_in[5];
    const float* bpre2 = (const float*)d_in[6];
    const float* Wc1   = (const float*)d_in[7];
    const float* bc1   = (const float*)d_in[8];
    const float* Wc2   = (const float*)d_in[9];
    const float* bc2   = (const float*)d_in[10];
    const float* Wm1   = (const float*)d_in[11];
    const float* bm1   = (const float*)d_in[12];
    const float* Wm2   = (const float*)d_in[13];
    const float* bm2   = (const float*)d_in[14];
    const float* Wpost = (const float*)d_in[15];
    const float* bpost = (const float*)d_in[16];
    const int* edge_index = (const int*)d_in[17];
    const int* eli        = (const int*)d_in[18];

    const int N = in_sizes[0] / 256;   // 50000  (must be <= 65536 for packing)
    const int E = in_sizes[17] / 2;    // 1.6M
    const int L = in_sizes[18] / 2;    // 200K
    const int NB = (N + 255) >> BSHIFT;

    const int* src = edge_index;
    const int* dst = edge_index + E;

    float* out  = (float*)d_out;
    float* pred = out;                        // [L]
    float* emb0 = out + L;                    // [N,128]
    float* emb1 = out + L + (size_t)N * 128;  // [N,64]

    // ---- workspace layout (float slots); all regions disjoint in time ----
    float* ws = (float*)d_ws;
    ushort_t* h1h   = (ushort_t*)ws;                       // [0,128N)
    ushort_t* hws1b = (ushort_t*)ws;                       // [0,64N)
    ushort_t* emb0b = (ushort_t*)ws;                       // [0,64N)
    ushort_t* emb1b = (ushort_t*)ws;                       // [0,32N)
    ushort_t* agg1b = (ushort_t*)(ws + (size_t)64 * N);    // [64N,128N)
    ushort_t* hws2b = (ushort_t*)(ws + (size_t)64 * N);    // [64N,96N)
    ushort_t* agg2b = (ushort_t*)(ws + (size_t)96 * N);    // [96N,128N)
    ushort_t* h2b   = (ushort_t*)(ws + (size_t)128 * N);   // [128N,192N)

    size_t o = (size_t)192 * N;
    unsigned* packed = (unsigned*)(ws + o); o += ((size_t)E + 3) & ~(size_t)3;
    int* col = (int*)(ws + o);              o += ((size_t)E + 3) & ~(size_t)3;
    int* rowstart = (int*)(ws + o);         o += ((size_t)N + 4) & ~(size_t)3;
    float* dinv = ws + o;                   o += ((size_t)N + 3) & ~(size_t)3;
    int* bbase = (int*)(ws + o);            o += 260;
    int* bcursor = (int*)(ws + o);          o += 260;
    int* bcount = (int*)(ws + o);           o += 260;
    ushort_t* wb = (ushort_t*)(ws + o);     // 327680 ushorts (16B-aligned)

    ushort_t* wpre1h = wb + 0;       ushort_t* wpre1l = wb + 65536;
    ushort_t* wpre2h = wb + 131072;  ushort_t* wpre2l = wb + 163840;
    ushort_t* wc1h   = wb + 196608;  ushort_t* wc1l   = wb + 212992;
    ushort_t* wm1h   = wb + 229376;  ushort_t* wm1l   = wb + 262144;
    ushort_t* wc2h   = wb + 294912;  ushort_t* wc2l   = wb + 303104;
    ushort_t* wm2h   = wb + 311296;  ushort_t* wm2l   = wb + 319488;

    // 0) bucketed CSR build + dinv
    hipMemsetAsync(bcount, 0, (size_t)NB * sizeof(int), stream);
    bcount_kernel<<<1024, 256, 0, stream>>>(dst, bcount, E, NB);
    bscan_kernel<<<1, 256, 0, stream>>>(bcount, bbase, bcursor, NB, E);
    bpart_kernel<<<(E + 8191) / 8192, 256, 0, stream>>>(src, dst, bcursor, packed, E, NB);
    bbuild_kernel<<<NB, 256, 0, stream>>>(bbase, packed, col, rowstart, dinv, N, E);

    // 0b) weights: transpose + hi/lo split into fragment-major layout
    WAll wa;
    wa.d[0] = {Wpre1, wpre1h, wpre1l, 256, 256};
    wa.d[1] = {Wpre2, wpre2h, wpre2l, 256, 128};
    wa.d[2] = {Wc1,   wc1h,   wc1l,   128, 128};
    wa.d[3] = {Wm1,   wm1h,   wm1l,   256, 128};
    wa.d[4] = {Wc2,   wc2h,   wc2l,   128, 64};
    wa.d[5] = {Wm2,   wm2h,   wm2l,   128, 64};
    wtcvt_kernel<<<dim3(256, 6), 256, 0, stream>>>(wa);

    const int gt = (N + 31) / 32;   // 1563 row-tiles

    // 1) h1 = bf16(relu(x@Wpre1+b))           [N,256]  K=256, fp32 A
    gemm_reg<4, 256, 256, true, false, false, false, 2><<<gt, 256, 0, stream>>>(
        x, nullptr, nullptr, wpre1h, wpre1l, bpre1, nullptr, nullptr, h1h, N, 256);
    // 2) h2 = bf16(relu(h1@Wpre2+b))          [N,128]  K=256, bf16 A
    gemm_reg<2, 256, 256, true, false, false, true, 2><<<gt, 256, 0, stream>>>(
        nullptr, h1h, nullptr, wpre2h, wpre2l, bpre2, nullptr, nullptr, h2b, N, 128);
    // 3) hws1 = bf16((h2@Wc1)*dinv[row])      [N,128]  K=128  (h1 dead)
    gemm_reg<2, 128, 128, false, true, false, true, 2><<<gt, 256, 0, stream>>>(
        nullptr, h2b, nullptr, wc1h, wc1l, nullptr, dinv, nullptr, hws1b, N, 128);
    // 4) agg1 = bf16(relu(dinv*(hws1[d]+sum hws1[s])+bc1))
    gather_bf_kernel<128><<<(N + 3) / 4, 256, 0, stream>>>(rowstart, col, dinv, hws1b, bc1, agg1b, N);
    // 5) emb0 = [agg1,prev0]@Wm1+bm1 (fp32 + bf16 copy)  [N,128]  K=128+128
    gemm_reg<2, 256, 128, false, false, true, true, 3><<<gt, 256, 0, stream>>>(
        nullptr, agg1b, prev0, wm1h, wm1l, bm1, nullptr, emb0, emb0b, N, 128);
    // 6) hws2 = bf16((emb0@Wc2)*dinv[row])    [N,64]   K=128, bf16 A
    gemm_reg<1, 128, 128, false, true, false, true, 2><<<gt, 256, 0, stream>>>(
        nullptr, emb0b, nullptr, wc2h, wc2l, nullptr, dinv, nullptr, hws2b, N, 64);
    // 7) agg2 = bf16(relu(dinv*(hws2[d]+sum hws2[s])+bc2))
    gather_bf_kernel<64><<<(N + 3) / 4, 256, 0, stream>>>(rowstart, col, dinv, hws2b, bc2, agg2b, N);
    // 8) emb1 = [agg2,prev1]@Wm2+bm2 (fp32 + bf16 copy)  [N,64]  K=64+64
    gemm_reg<1, 128, 64, false, false, true, true, 3><<<gt, 256, 0, stream>>>(
        nullptr, agg2b, prev1, wm2h, wm2l, bm2, nullptr, emb1, emb1b, N, 64);
    // 9) decode (bf16 emb1 copy, L2-resident)
    decode_kernel<<<(L + 3) / 4, 256, 0, stream>>>(emb1b, eli, Wpost, bpost, pred, L);
}